// Round 1
// baseline (99.669 us; speedup 1.0000x reference)
//
#include <hip/hip_runtime.h>
#include <hip/hip_bf16.h>

// MinibatchDiscrimination: B=512, IN=512, OUT=64, KD=8 (all fp32)
// out[i, 0:512]   = x[i, :]
// out[i, 512+o]   = sum_j exp(-sum_k |M[i,o,k] - M[j,o,k]|),  M = x @ T
//
// Plan:
//  K1 fill_out : copy x into out cols [0,512), zero cols [512,576) (atomics target)
//  K2 gemm     : M^T layout [OUT][B][KD] into d_ws (16KB contiguous per-o slice)
//  K3 pairs    : block = (o, i-tile-of-256, j-half); full per-o slice in LDS (16KB),
//                inner loop LDS reads are wave-uniform (broadcast, conflict-free),
//                atomicAdd the j-half partial into out.

#define B_  512
#define IN_ 512
#define OUT_ 64
#define KD_ 8
#define ROW_ (IN_ + OUT_)   // 576 floats per output row
#define ROW4_ (ROW_ / 4)    // 144 float4 per output row

__global__ __launch_bounds__(256)
void fill_out_kernel(const float* __restrict__ x, float* __restrict__ out) {
    int v = blockIdx.x * 256 + threadIdx.x;      // [0, 512*144)
    if (v >= B_ * ROW4_) return;
    int i  = v / ROW4_;
    int c4 = v - i * ROW4_;
    float4 val;
    if (c4 < IN_ / 4) {
        val = ((const float4*)x)[i * (IN_ / 4) + c4];
    } else {
        val = make_float4(0.f, 0.f, 0.f, 0.f);
    }
    ((float4*)out)[v] = val;
}

// C[i, oc] = sum_c x[i,c] * T[c, oc], oc in [0,512); write transposed:
// Mt[(oc>>3)*B*KD + i*KD + (oc&7)]
__global__ __launch_bounds__(256)
void gemm_kernel(const float* __restrict__ x, const float* __restrict__ T,
                 float* __restrict__ Mt) {
    __shared__ float As[16][17];
    __shared__ float Bs[16][17];
    int tx = threadIdx.x, ty = threadIdx.y;
    int row = blockIdx.y * 16 + ty;   // i
    int col = blockIdx.x * 16 + tx;   // oc
    float acc = 0.f;
    for (int t = 0; t < IN_; t += 16) {
        As[ty][tx] = x[row * IN_ + t + tx];
        Bs[ty][tx] = T[(t + ty) * (OUT_ * KD_) + col];
        __syncthreads();
        #pragma unroll
        for (int k = 0; k < 16; ++k)
            acc = fmaf(As[ty][k], Bs[k][tx], acc);
        __syncthreads();
    }
    Mt[(col >> 3) * (B_ * KD_) + row * KD_ + (col & 7)] = acc;
}

// grid.x = OUT_ * 2 (itile) * 2 (jhalf) = 256 blocks, 256 threads
__global__ __launch_bounds__(256)
void pairs_kernel(const float* __restrict__ Mt, float* __restrict__ out) {
    int b      = blockIdx.x;
    int o      = b >> 2;
    int itile  = (b >> 1) & 1;
    int jhalf  = b & 1;

    __shared__ float s[B_ * KD_];     // 16 KB: full M[:, o, :] slice
    const float4* src = (const float4*)(Mt + o * (B_ * KD_));
    #pragma unroll
    for (int v = threadIdx.x; v < (B_ * KD_) / 4; v += 256)
        ((float4*)s)[v] = src[v];
    __syncthreads();

    int i = itile * 256 + threadIdx.x;
    float mi[KD_];
    #pragma unroll
    for (int k = 0; k < KD_; ++k) mi[k] = s[i * KD_ + k];

    float acc = 0.f;
    int j0 = jhalf * 256;
    #pragma unroll 4
    for (int j = j0; j < j0 + 256; ++j) {
        float d = 0.f;
        #pragma unroll
        for (int k = 0; k < KD_; ++k)
            d += fabsf(mi[k] - s[j * KD_ + k]);
        acc += __expf(-d);
    }
    atomicAdd(&out[i * ROW_ + IN_ + o], acc);
}

extern "C" void kernel_launch(void* const* d_in, const int* in_sizes, int n_in,
                              void* d_out, int out_size, void* d_ws, size_t ws_size,
                              hipStream_t stream) {
    const float* x = (const float*)d_in[0];   // [512, 512]
    const float* T = (const float*)d_in[1];   // [512, 64, 8] -> [512, 512] flat
    float* out = (float*)d_out;               // [512, 576]
    float* Mt  = (float*)d_ws;                // [64][512][8] = 1 MB

    // 1) copy x + zero the atomic-target columns
    {
        int total = B_ * ROW4_;               // 73728
        fill_out_kernel<<<(total + 255) / 256, 256, 0, stream>>>(x, out);
    }
    // 2) M = x @ T, transposed layout
    {
        dim3 grid(512 / 16, 512 / 16);
        dim3 block(16, 16);
        gemm_kernel<<<grid, block, 0, stream>>>(x, T, Mt);
    }
    // 3) all-pairs L1 + exp, partial sums via atomics
    {
        pairs_kernel<<<OUT_ * 4, 256, 0, stream>>>(Mt, out);
    }
}